// Round 11
// baseline (575.614 us; speedup 1.0000x reference)
//
#include <hip/hip_runtime.h>

#define DIM 128
#define NCLS 40
#define SCAN_B 1024

typedef unsigned short ushort_t;
typedef __attribute__((ext_vector_type(8))) short bf16x8;
typedef __attribute__((ext_vector_type(4))) float f32x4;
typedef __attribute__((ext_vector_type(4))) int i32x4;

__device__ __forceinline__ ushort_t f2b(float f) {
    union { float f; unsigned u; } v; v.f = f;
    unsigned r = v.u + 0x7FFFu + ((v.u >> 16) & 1u);   // round-to-nearest-even
    return (ushort_t)(r >> 16);
}

__device__ __forceinline__ float b2f(ushort_t b) {
    union { unsigned u; float f; } v; v.u = ((unsigned)b) << 16;
    return v.f;
}

// accumulate 4 fp8(e4m3) values packed in w into a float4
__device__ __forceinline__ void acc_fp8x4(float4& a, int w) {
    a.x += __builtin_amdgcn_cvt_f32_fp8(w, 0);
    a.y += __builtin_amdgcn_cvt_f32_fp8(w, 1);
    a.z += __builtin_amdgcn_cvt_f32_fp8(w, 2);
    a.w += __builtin_amdgcn_cvt_f32_fp8(w, 3);
}

// ---------------- fused prep: cast + packw + packw2 + deg-zero + ctr-zero ----
__global__ __launch_bounds__(256) void prep_kernel(
    const float* __restrict__ x, ushort_t* __restrict__ xbf, unsigned* __restrict__ xq,
    const float* __restrict__ W1r, const float* __restrict__ W1l, ushort_t* __restrict__ Wp,
    const float* __restrict__ W2l, ushort_t* __restrict__ Wp2,
    int* __restrict__ deg, int* __restrict__ ctr, int n4, int cb, int zb, int n)
{
    const int b = blockIdx.x;
    if (b < cb) {
        int i = b * 256 + threadIdx.x;
        if (i >= n4) return;
        f32x4 v = __builtin_nontemporal_load(((const f32x4*)x) + i);
        ushort4 o;
        o.x = f2b(v.x); o.y = f2b(v.y); o.z = f2b(v.z); o.w = f2b(v.w);
        ((ushort4*)xbf)[i] = o;
        int p = __builtin_amdgcn_cvt_pk_fp8_f32(v.x, v.y, 0, false);
        p = __builtin_amdgcn_cvt_pk_fp8_f32(v.z, v.w, p, true);
        xq[i] = (unsigned)p;
    } else if (b < cb + 128) {
        int o = (b - cb) * 256 + threadIdx.x;   // 0..32767
        int j    = o & 7;
        int lane = (o >> 3) & 63;
        int t    = (o >> 9) & 7;
        int kc   = o >> 12;
        int k = kc * 32 + (lane >> 4) * 8 + j;
        int nn = t * 16 + (lane & 15);
        float v = (k < DIM) ? W1r[k * DIM + nn] : W1l[(k - DIM) * DIM + nn];
        Wp[o] = f2b(v);
    } else if (b < cb + 152) {
        int o = (b - cb - 128) * 256 + threadIdx.x;   // 0..6143
        int j    = o & 7;
        int lane = (o >> 3) & 63;
        int rem  = o >> 9;
        int t    = rem % 3;
        int kc   = rem / 3;
        int k  = kc * 32 + (lane >> 4) * 8 + j;
        int nn = t * 16 + (lane & 15);
        Wp2[o] = (nn < NCLS) ? f2b(W2l[k * NCLS + nn]) : (ushort_t)0;
    } else {
        int i = (b - cb - 152) * 256 + threadIdx.x;
        if (i < n) deg[i] = 0;
        if (b == cb + 152 && threadIdx.x < 8) ctr[threadIdx.x] = 0;
    }
}

// ---------------- CSR build ----------------

__global__ __launch_bounds__(256) void hist_kernel(const int* __restrict__ dst,
                                                   int* __restrict__ deg, int E) {
    int e = blockIdx.x * 256 + threadIdx.x;
    if (e < E) atomicAdd(&deg[__builtin_nontemporal_load(dst + e)], 1);
}

__global__ __launch_bounds__(256) void scan1_kernel(const int* __restrict__ deg,
                                                    int* __restrict__ bsum, int n) {
    __shared__ int sh[256];
    int base = blockIdx.x * SCAN_B;
    int s = 0;
    for (int i = threadIdx.x; i < SCAN_B; i += 256) {
        int idx = base + i;
        if (idx < n) s += deg[idx];
    }
    sh[threadIdx.x] = s;
    __syncthreads();
    for (int off = 128; off > 0; off >>= 1) {
        if (threadIdx.x < off) sh[threadIdx.x] += sh[threadIdx.x + off];
        __syncthreads();
    }
    if (threadIdx.x == 0) bsum[blockIdx.x] = sh[0];
}

// per-chunk exclusive scan; each block serially prefixes bsum for its offset;
// last block writes row_ptr[n] = E.
__global__ __launch_bounds__(SCAN_B) void scan3_kernel(const int* __restrict__ deg,
                                                       const int* __restrict__ bsum,
                                                       int* __restrict__ row_ptr,
                                                       int* __restrict__ pos,
                                                       int n, int nb) {
    __shared__ int sh[SCAN_B];
    __shared__ int boff;
    int i = blockIdx.x * SCAN_B + threadIdx.x;
    int v = (i < n) ? deg[i] : 0;
    sh[threadIdx.x] = v;
    __syncthreads();
    for (int off = 1; off < SCAN_B; off <<= 1) {
        int t = (threadIdx.x >= off) ? sh[threadIdx.x - off] : 0;
        __syncthreads();
        sh[threadIdx.x] += t;
        __syncthreads();
    }
    if (threadIdx.x == 0) {
        int acc = 0;
        for (int b = 0; b < blockIdx.x; ++b) acc += bsum[b];
        boff = acc;
        if (blockIdx.x == (unsigned)(nb - 1)) {
            int tot = acc;
            for (int b = blockIdx.x; b < nb; ++b) tot += bsum[b];
            row_ptr[n] = tot;   // == E
        }
    }
    __syncthreads();
    if (i < n) {
        int rp = sh[threadIdx.x] - v + boff;
        row_ptr[i] = rp;
        pos[i] = rp;        // fill bumps pos directly -> absolute slot
    }
}

// HW-XCD-bound bucketed fill with chunk claiming + work stealing.
// Each block reads its physical XCD id (HW_REG_XCC_ID=20) and processes the
// matching dst-range bucket first, claiming 4096-edge chunks from a per-bucket
// counter; after its bucket drains it steals remaining chunks of other buckets.
// Every chunk is processed exactly once regardless of the XCC_ID values, so
// correctness never depends on the mapping — only write locality does.
__global__ __launch_bounds__(256) void fill_kernel(const int* __restrict__ src,
                                                   const int* __restrict__ dst,
                                                   int* __restrict__ pos,
                                                   int* __restrict__ eidx,
                                                   int* __restrict__ ctr,
                                                   int E, int n) {
    __shared__ int sc;
    const int xcc = __builtin_amdgcn_s_getreg(63508) & 7;  // id20, off0, size32
    const int bsz = (n + 7) / 8;
    for (int bi = 0; bi < 8; ++bi) {
        const int b = (xcc + bi) & 7;
        const int lo_n = b * bsz;
        const int hi_n = min(lo_n + bsz, n);
        while (true) {
            __syncthreads();
            if (threadIdx.x == 0) sc = atomicAdd(&ctr[b], 1);
            __syncthreads();
            const int c = sc;
            const long long elo = (long long)c * 4096;
            if (elo >= E) break;
            const int ehi = min((int)(elo + 4096), E);
            for (int e4 = ((int)elo >> 2) + threadIdx.x; e4 < (ehi >> 2); e4 += 256) {
                i32x4 d4 = __builtin_nontemporal_load((const i32x4*)dst + e4);
                #pragma unroll
                for (int i = 0; i < 4; ++i) {
                    int d = d4[i];
                    if (d >= lo_n && d < hi_n) {
                        int p = atomicAdd(&pos[d], 1);
                        eidx[p] = __builtin_nontemporal_load(src + e4 * 4 + i);
                    }
                }
            }
        }
    }
}

// ---------------- compute ----------------

// mxbf[node] = mean over CSR neighbors of xq[src] (fp8 in, fp32 accum, bf16 out)
__global__ __launch_bounds__(256) void gather128_kernel(
    const unsigned* __restrict__ xq, const int* __restrict__ row_ptr,
    const int* __restrict__ eidx, ushort_t* __restrict__ Bbf, int n)
{
    int t = blockIdx.x * 256 + threadIdx.x;
    int node = t >> 5;
    if (node >= n) return;
    int q = t & 31;
    int j  = row_ptr[node];
    int je = row_ptr[node + 1];
    const float id = 1.0f / fmaxf((float)(je - j), 1.0f);
    float4 acc = make_float4(0.f, 0.f, 0.f, 0.f);
    for (; j + 3 < je; j += 4) {
        int s0 = eidx[j], s1 = eidx[j + 1], s2 = eidx[j + 2], s3 = eidx[j + 3];
        int w0 = (int)xq[(size_t)s0 * 32 + q];
        int w1 = (int)xq[(size_t)s1 * 32 + q];
        int w2 = (int)xq[(size_t)s2 * 32 + q];
        int w3 = (int)xq[(size_t)s3 * 32 + q];
        acc_fp8x4(acc, w0); acc_fp8x4(acc, w1);
        acc_fp8x4(acc, w2); acc_fp8x4(acc, w3);
    }
    for (; j < je; ++j) {
        int s0 = eidx[j];
        acc_fp8x4(acc, (int)xq[(size_t)s0 * 32 + q]);
    }
    ushort4 o;
    o.x = f2b(acc.x * id); o.y = f2b(acc.y * id);
    o.z = f2b(acc.z * id); o.w = f2b(acc.w * id);
    ((ushort4*)(Bbf + (size_t)node * DIM))[q] = o;
}

// Fused layer-1 + layer-2-left (unchanged from R10)
__global__ __launch_bounds__(256) void mfma_gemm_kernel(
    const ushort_t* __restrict__ xbf, const ushort_t* __restrict__ mxbf,
    const ushort_t* __restrict__ Wp, const ushort_t* __restrict__ Wp2,
    const float* __restrict__ bias,
    ushort_t* __restrict__ Hbf, ushort_t* __restrict__ Cbf, int n)
{
    __shared__ ushort_t hl[4][16 * 136];   // 16 rows x 136 (pad 8) bf16 per wave
    const int wave = threadIdx.x >> 6;
    const int lane = threadIdx.x & 63;
    const int m16  = lane & 15;
    const int quad = lane >> 4;
    const int row0 = blockIdx.x * 64 + wave * 16;
    int arow = row0 + m16;
    if (arow >= n) arow = n - 1;          // clamp; OOB rows never stored
    f32x4 acc[8];
    #pragma unroll
    for (int t = 0; t < 8; ++t) acc[t] = (f32x4){0.f, 0.f, 0.f, 0.f};
    const ushort_t* __restrict__ xrow = xbf  + (size_t)arow * DIM;
    const ushort_t* __restrict__ mrow = mxbf + (size_t)arow * DIM;
    #pragma unroll
    for (int kc = 0; kc < 8; ++kc) {
        const int kcol = (kc & 3) * 32 + quad * 8;
        const bf16x8 afrag = *(const bf16x8*)((kc < 4 ? xrow : mrow) + kcol);
        const ushort_t* __restrict__ wp = Wp + (size_t)kc * 4096 + (size_t)lane * 8;
        #pragma unroll
        for (int t = 0; t < 8; ++t) {
            const bf16x8 bfrag = *(const bf16x8*)(wp + (size_t)t * 512);
            acc[t] = __builtin_amdgcn_mfma_f32_16x16x32_bf16(afrag, bfrag, acc[t], 0, 0, 0);
        }
    }
    ushort_t* __restrict__ hw = hl[wave];
    #pragma unroll
    for (int t = 0; t < 8; ++t) {
        const int col = t * 16 + m16;
        const float bv = bias[col];
        #pragma unroll
        for (int r = 0; r < 4; ++r) {
            hw[(quad * 4 + r) * 136 + col] = f2b(fmaxf(acc[t][r] + bv, 0.f));
        }
    }
    f32x4 acc2[3];
    #pragma unroll
    for (int t = 0; t < 3; ++t) acc2[t] = (f32x4){0.f, 0.f, 0.f, 0.f};
    const bool rowok = (row0 + m16) < n;
    #pragma unroll
    for (int kc = 0; kc < 4; ++kc) {
        const bf16x8 afrag2 = *(const bf16x8*)(hw + m16 * 136 + kc * 32 + quad * 8);
        if (rowok)
            *(bf16x8*)(Hbf + (size_t)(row0 + m16) * DIM + kc * 32 + quad * 8) = afrag2;
        const ushort_t* __restrict__ wp2 = Wp2 + (size_t)kc * 1536 + (size_t)lane * 8;
        #pragma unroll
        for (int t = 0; t < 3; ++t) {
            const bf16x8 bfrag = *(const bf16x8*)(wp2 + (size_t)t * 512);
            acc2[t] = __builtin_amdgcn_mfma_f32_16x16x32_bf16(afrag2, bfrag, acc2[t], 0, 0, 0);
        }
    }
    #pragma unroll
    for (int t = 0; t < 3; ++t) {
        const int col = t * 16 + m16;
        if (col >= NCLS) continue;
        #pragma unroll
        for (int r = 0; r < 4; ++r) {
            const int row = row0 + quad * 4 + r;
            if (row < n) Cbf[(size_t)row * NCLS + col] = f2b(acc2[t][r]);
        }
    }
}

// Fused layer-2 gather + right-branch + softmax, 5 lanes per node (8 classes each).
// Neighbor row (80B) read as 5 x bf16x8 across the group (coalesced);
// softmax max/sum via 5-lane shuffles; out row written as 5 x 32B (coalesced).
__global__ __launch_bounds__(256) void final_kernel(
    const ushort_t* __restrict__ Hbf, const ushort_t* __restrict__ Cbf,
    const int* __restrict__ row_ptr, const int* __restrict__ eidx,
    const float* __restrict__ W, const float* __restrict__ b2,
    float* __restrict__ out, int n)
{
    const int wave = threadIdx.x >> 6;
    const int lane = threadIdx.x & 63;
    const int g    = lane / 5;           // 0..11 (lanes 60-63 idle)
    const int slot = lane - g * 5;       // 0..4 -> classes [slot*8, slot*8+8)
    if (g >= 12) return;
    const int nd = blockIdx.x * 48 + wave * 12 + g;
    if (nd >= n) return;
    int j  = row_ptr[nd];
    int je = row_ptr[nd + 1];
    const float id = 1.0f / fmaxf((float)(je - j), 1.0f);
    float lg[8];
    #pragma unroll
    for (int c = 0; c < 8; ++c) lg[c] = 0.f;
    for (; j < je; ++j) {
        int s = eidx[j];
        bf16x8 v = *(const bf16x8*)(Cbf + (size_t)s * NCLS + slot * 8);
        #pragma unroll
        for (int c = 0; c < 8; ++c) lg[c] += b2f((ushort_t)v[c]);
    }
    const float* __restrict__ bq = b2 + slot * 8;
    #pragma unroll
    for (int c = 0; c < 8; ++c) lg[c] = fmaf(lg[c], id, bq[c]);
    // right branch: h[nd] @ W2_r columns [slot*8, slot*8+8)
    const ushort_t* __restrict__ h = Hbf + (size_t)nd * DIM;
    for (int k = 0; k < DIM; k += 8) {
        bf16x8 hv = *(const bf16x8*)(h + k);
        #pragma unroll
        for (int kk = 0; kk < 8; ++kk) {
            const float hk = b2f((ushort_t)hv[kk]);
            const float* __restrict__ w = W + (size_t)(k + kk) * NCLS + slot * 8;
            #pragma unroll
            for (int c = 0; c < 8; ++c) lg[c] = fmaf(hk, w[c], lg[c]);
        }
    }
    // group softmax
    float m = lg[0];
    #pragma unroll
    for (int c = 1; c < 8; ++c) m = fmaxf(m, lg[c]);
    float gm = m;
    #pragma unroll
    for (int k = 0; k < 5; ++k) gm = fmaxf(gm, __shfl(m, g * 5 + k));
    float s = 0.f;
    #pragma unroll
    for (int c = 0; c < 8; ++c) { lg[c] = __expf(lg[c] - gm); s += lg[c]; }
    float gs = 0.f;
    #pragma unroll
    for (int k = 0; k < 5; ++k) gs += __shfl(s, g * 5 + k);
    const float inv = 1.0f / gs;
    float* __restrict__ o = out + (size_t)nd * NCLS + slot * 8;
    #pragma unroll
    for (int c = 0; c < 8; c += 4) {
        float4 ov = make_float4(lg[c] * inv, lg[c+1] * inv, lg[c+2] * inv, lg[c+3] * inv);
        *(float4*)(o + c) = ov;
    }
}

extern "C" void kernel_launch(void* const* d_in, const int* in_sizes, int n_in,
                              void* d_out, int out_size, void* d_ws, size_t ws_size,
                              hipStream_t stream) {
    const float* x   = (const float*)d_in[0];
    const int*   ei  = (const int*)d_in[1];
    const float* W1l = (const float*)d_in[2];
    const float* W1r = (const float*)d_in[3];
    const float* b1  = (const float*)d_in[4];
    const float* W2l = (const float*)d_in[5];
    const float* W2r = (const float*)d_in[6];
    const float* b2  = (const float*)d_in[7];
    float* out = (float*)d_out;

    const int n = in_sizes[0] / DIM;   // 100000
    const int E = in_sizes[1] / 2;     // 1600000
    const int* src = ei;
    const int* dst = ei + E;
    const int nb = (n + SCAN_B - 1) / SCAN_B;   // 98 scan blocks

    // workspace layout (~105 MB):
    //   xbf (25.6MB) | mxbf (25.6MB) | Hbf (25.6MB) | Cbf (8MB) | xq (12.8MB fp8)
    //   | Wp | Wp2 | eidx[E] | row_ptr[n+1] | deg[n] | pos[n] | bsum[128] | ctr[8]
    ushort_t* xbf     = (ushort_t*)d_ws;
    ushort_t* mxbf    = xbf + (size_t)n * DIM;
    ushort_t* Hbf     = mxbf + (size_t)n * DIM;
    ushort_t* Cbf     = Hbf + (size_t)n * DIM;
    unsigned* xq      = (unsigned*)(Cbf + (size_t)n * NCLS);
    ushort_t* Wp      = (ushort_t*)(xq + (size_t)n * 32);
    ushort_t* Wp2     = Wp + 256 * DIM;
    int*      eidx    = (int*)(Wp2 + 4 * 1536);
    int*      row_ptr = eidx + E;
    int*      deg     = row_ptr + (n + 1);
    int*      pos     = deg + n;
    int*      bsum    = pos + n;
    int*      ctr     = bsum + 128;

    // --- fused prep (cast + weight packs + deg/ctr zero) ---
    const int n4 = n * 32;                       // float4 items in x
    const int cb = (n4 + 255) / 256;             // cast blocks
    const int zb = (n + 255) / 256;              // deg-zero blocks
    prep_kernel<<<cb + 152 + zb, 256, 0, stream>>>(x, xbf, xq, W1r, W1l, Wp,
                                                   W2l, Wp2, deg, ctr, n4, cb, zb, n);

    // --- CSR build ---
    hist_kernel <<<(E + 255) / 256, 256, 0, stream>>>(dst, deg, E);
    scan1_kernel<<<nb, 256, 0, stream>>>(deg, bsum, n);
    scan3_kernel<<<nb, SCAN_B, 0, stream>>>(deg, bsum, row_ptr, pos, n, nb);
    fill_kernel <<<1024, 256, 0, stream>>>(src, dst, pos, eidx, ctr, E, n);

    // --- layer 1 + layer-2-left (fused) ---
    {
        long long t = (long long)n * 32;
        gather128_kernel<<<(int)((t + 255) / 256), 256, 0, stream>>>(xq, row_ptr, eidx, mxbf, n);
    }
    mfma_gemm_kernel<<<(n + 63) / 64, 256, 0, stream>>>(xbf, mxbf, Wp, Wp2, b1, Hbf, Cbf, n);

    // --- layer 2: fused gather + right-branch + softmax ---
    final_kernel<<<(n + 47) / 48, 256, 0, stream>>>(Hbf, Cbf, row_ptr, eidx, W2r, b2, out, n);
}

// Round 12
// 418.803 us; speedup vs baseline: 1.3744x; 1.3744x over previous
//
#include <hip/hip_runtime.h>

#define DIM 128
#define NCLS 40
#define SCAN_B 1024

typedef unsigned short ushort_t;
typedef __attribute__((ext_vector_type(8))) short bf16x8;
typedef __attribute__((ext_vector_type(4))) float f32x4;

__device__ __forceinline__ ushort_t f2b(float f) {
    union { float f; unsigned u; } v; v.f = f;
    unsigned r = v.u + 0x7FFFu + ((v.u >> 16) & 1u);   // round-to-nearest-even
    return (ushort_t)(r >> 16);
}

__device__ __forceinline__ float b2f(ushort_t b) {
    union { unsigned u; float f; } v; v.u = ((unsigned)b) << 16;
    return v.f;
}

// accumulate 4 fp8(e4m3) values packed in w into a float4
__device__ __forceinline__ void acc_fp8x4(float4& a, int w) {
    a.x += __builtin_amdgcn_cvt_f32_fp8(w, 0);
    a.y += __builtin_amdgcn_cvt_f32_fp8(w, 1);
    a.z += __builtin_amdgcn_cvt_f32_fp8(w, 2);
    a.w += __builtin_amdgcn_cvt_f32_fp8(w, 3);
}

// ---------------- fused prep: cast + packw + packw2 + deg-zero ----------------
__global__ __launch_bounds__(256) void prep_kernel(
    const float* __restrict__ x, ushort_t* __restrict__ xbf, unsigned* __restrict__ xq,
    const float* __restrict__ W1r, const float* __restrict__ W1l, ushort_t* __restrict__ Wp,
    const float* __restrict__ W2l, ushort_t* __restrict__ Wp2,
    int* __restrict__ deg, int n4, int cb, int zb, int n)
{
    const int b = blockIdx.x;
    if (b < cb) {
        int i = b * 256 + threadIdx.x;
        if (i >= n4) return;
        f32x4 v = __builtin_nontemporal_load(((const f32x4*)x) + i);
        ushort4 o;
        o.x = f2b(v.x); o.y = f2b(v.y); o.z = f2b(v.z); o.w = f2b(v.w);
        ((ushort4*)xbf)[i] = o;
        int p = __builtin_amdgcn_cvt_pk_fp8_f32(v.x, v.y, 0, false);
        p = __builtin_amdgcn_cvt_pk_fp8_f32(v.z, v.w, p, true);
        xq[i] = (unsigned)p;
    } else if (b < cb + 128) {
        int o = (b - cb) * 256 + threadIdx.x;   // 0..32767
        int j    = o & 7;
        int lane = (o >> 3) & 63;
        int t    = (o >> 9) & 7;
        int kc   = o >> 12;
        int k = kc * 32 + (lane >> 4) * 8 + j;
        int nn = t * 16 + (lane & 15);
        float v = (k < DIM) ? W1r[k * DIM + nn] : W1l[(k - DIM) * DIM + nn];
        Wp[o] = f2b(v);
    } else if (b < cb + 152) {
        int o = (b - cb - 128) * 256 + threadIdx.x;   // 0..6143
        int j    = o & 7;
        int lane = (o >> 3) & 63;
        int rem  = o >> 9;
        int t    = rem % 3;
        int kc   = rem / 3;
        int k  = kc * 32 + (lane >> 4) * 8 + j;
        int nn = t * 16 + (lane & 15);
        Wp2[o] = (nn < NCLS) ? f2b(W2l[k * NCLS + nn]) : (ushort_t)0;
    } else {
        int i = (b - cb - 152) * 256 + threadIdx.x;
        if (i < n) deg[i] = 0;
    }
}

// ---------------- CSR build ----------------

__global__ __launch_bounds__(256) void hist_kernel(const int* __restrict__ dst,
                                                   int* __restrict__ deg, int E) {
    int e = blockIdx.x * 256 + threadIdx.x;
    if (e < E) atomicAdd(&deg[__builtin_nontemporal_load(dst + e)], 1);
}

__global__ __launch_bounds__(256) void scan1_kernel(const int* __restrict__ deg,
                                                    int* __restrict__ bsum, int n) {
    __shared__ int sh[256];
    int base = blockIdx.x * SCAN_B;
    int s = 0;
    for (int i = threadIdx.x; i < SCAN_B; i += 256) {
        int idx = base + i;
        if (idx < n) s += deg[idx];
    }
    sh[threadIdx.x] = s;
    __syncthreads();
    for (int off = 128; off > 0; off >>= 1) {
        if (threadIdx.x < off) sh[threadIdx.x] += sh[threadIdx.x + off];
        __syncthreads();
    }
    if (threadIdx.x == 0) bsum[blockIdx.x] = sh[0];
}

// per-chunk exclusive scan; each block serially prefixes bsum for its offset;
// last block writes row_ptr[n] = E.
__global__ __launch_bounds__(SCAN_B) void scan3_kernel(const int* __restrict__ deg,
                                                       const int* __restrict__ bsum,
                                                       int* __restrict__ row_ptr,
                                                       int* __restrict__ pos,
                                                       int n, int nb) {
    __shared__ int sh[SCAN_B];
    __shared__ int boff;
    int i = blockIdx.x * SCAN_B + threadIdx.x;
    int v = (i < n) ? deg[i] : 0;
    sh[threadIdx.x] = v;
    __syncthreads();
    for (int off = 1; off < SCAN_B; off <<= 1) {
        int t = (threadIdx.x >= off) ? sh[threadIdx.x - off] : 0;
        __syncthreads();
        sh[threadIdx.x] += t;
        __syncthreads();
    }
    if (threadIdx.x == 0) {
        int acc = 0;
        for (int b = 0; b < blockIdx.x; ++b) acc += bsum[b];
        boff = acc;
        if (blockIdx.x == (unsigned)(nb - 1)) {
            int tot = acc;
            for (int b = blockIdx.x; b < nb; ++b) tot += bsum[b];
            row_ptr[n] = tot;   // == E
        }
    }
    __syncthreads();
    if (i < n) {
        int rp = sh[threadIdx.x] - v + boff;
        row_ptr[i] = rp;
        pos[i] = rp;        // fill bumps pos directly -> absolute slot
    }
}

// R10 fill (proven 75us): %8 bucketing, NT streaming loads.
__global__ __launch_bounds__(256) void fill_kernel(const int* __restrict__ src,
                                                   const int* __restrict__ dst,
                                                   int* __restrict__ pos,
                                                   int* __restrict__ eidx,
                                                   int E, int n) {
    const int buck = blockIdx.x & 7;
    const int bsz = (n + 7) / 8;
    const int lo = buck * bsz;
    const int hi = lo + bsz;
    const int bid = blockIdx.x >> 3;
    const int nb  = gridDim.x >> 3;
    const int tid = bid * 256 + threadIdx.x;
    const int stride = nb * 256;
    for (int e = tid; e < E; e += stride) {
        int d = __builtin_nontemporal_load(dst + e);
        if (d >= lo && d < hi) {
            int p = atomicAdd(&pos[d], 1);
            eidx[p] = __builtin_nontemporal_load(src + e);
        }
    }
}

// ---------------- compute ----------------

// Fused: gather128 prologue (per-wave, into LDS) + layer-1 GEMM + layer-2-left.
//   mx_tile = mean_{s in N(nd)} fp8(x[s])        (per-wave 16 rows, LDS bf16)
//   h  = relu([xbf | mx_tile] @ Wp + b1)         (K=256, 8 MFMA accums/wave)
//   Hbf = bf16(h); Cbf = bf16(h @ W2_l)
// Each wave writes/reads only its own LDS tiles -> no __syncthreads.
__global__ __launch_bounds__(256) void mfma_gemm_kernel(
    const ushort_t* __restrict__ xbf, const unsigned* __restrict__ xq,
    const int* __restrict__ row_ptr, const int* __restrict__ eidx,
    const ushort_t* __restrict__ Wp, const ushort_t* __restrict__ Wp2,
    const float* __restrict__ bias,
    ushort_t* __restrict__ Hbf, ushort_t* __restrict__ Cbf, int n)
{
    __shared__ ushort_t mx[4][16 * 136];   // aggregated-x tile (pad 8 -> 2-way free)
    __shared__ ushort_t hl[4][16 * 136];   // h tile for the second GEMM
    const int wave = threadIdx.x >> 6;
    const int lane = threadIdx.x & 63;
    const int m16  = lane & 15;
    const int quad = lane >> 4;
    const int row0 = blockIdx.x * 64 + wave * 16;

    // ---- gather prologue: 2 nodes per iter (32 lanes each), 8 iters = 16 rows
    ushort_t* __restrict__ mw = mx[wave];
    {
        const int q    = lane & 31;
        const int nsel = lane >> 5;
        for (int i = 0; i < 8; ++i) {
            const int lrow = i * 2 + nsel;
            int nd = row0 + lrow;
            if (nd >= n) nd = n - 1;         // clamped rows never stored
            int j  = row_ptr[nd];
            int je = row_ptr[nd + 1];
            const float id = 1.0f / fmaxf((float)(je - j), 1.0f);
            float4 acc = make_float4(0.f, 0.f, 0.f, 0.f);
            for (; j + 3 < je; j += 4) {
                int s0 = eidx[j], s1 = eidx[j + 1], s2 = eidx[j + 2], s3 = eidx[j + 3];
                acc_fp8x4(acc, (int)xq[(size_t)s0 * 32 + q]);
                acc_fp8x4(acc, (int)xq[(size_t)s1 * 32 + q]);
                acc_fp8x4(acc, (int)xq[(size_t)s2 * 32 + q]);
                acc_fp8x4(acc, (int)xq[(size_t)s3 * 32 + q]);
            }
            for (; j < je; ++j)
                acc_fp8x4(acc, (int)xq[(size_t)eidx[j] * 32 + q]);
            ushort4 o;
            o.x = f2b(acc.x * id); o.y = f2b(acc.y * id);
            o.z = f2b(acc.z * id); o.w = f2b(acc.w * id);
            *(ushort4*)(mw + lrow * 136 + q * 4) = o;
        }
    }

    // ---- layer-1 GEMM: K=256 = [x (global) | mean-x (LDS)]
    int arow = row0 + m16;
    if (arow >= n) arow = n - 1;
    f32x4 acc[8];
    #pragma unroll
    for (int t = 0; t < 8; ++t) acc[t] = (f32x4){0.f, 0.f, 0.f, 0.f};
    const ushort_t* __restrict__ xrow = xbf + (size_t)arow * DIM;
    #pragma unroll
    for (int kc = 0; kc < 8; ++kc) {
        const int kcol = (kc & 3) * 32 + quad * 8;
        const bf16x8 afrag = (kc < 4)
            ? *(const bf16x8*)(xrow + kcol)
            : *(const bf16x8*)(mw + m16 * 136 + kcol);
        const ushort_t* __restrict__ wp = Wp + (size_t)kc * 4096 + (size_t)lane * 8;
        #pragma unroll
        for (int t = 0; t < 8; ++t) {
            const bf16x8 bfrag = *(const bf16x8*)(wp + (size_t)t * 512);
            acc[t] = __builtin_amdgcn_mfma_f32_16x16x32_bf16(afrag, bfrag, acc[t], 0, 0, 0);
        }
    }
    // epilogue 1: relu+bias -> h tile in LDS
    ushort_t* __restrict__ hw = hl[wave];
    #pragma unroll
    for (int t = 0; t < 8; ++t) {
        const int col = t * 16 + m16;
        const float bv = bias[col];
        #pragma unroll
        for (int r = 0; r < 4; ++r) {
            hw[(quad * 4 + r) * 136 + col] = f2b(fmaxf(acc[t][r] + bv, 0.f));
        }
    }
    // second GEMM: C_tile = h_tile @ W2_l   (K=128 -> 4 chunks)
    f32x4 acc2[3];
    #pragma unroll
    for (int t = 0; t < 3; ++t) acc2[t] = (f32x4){0.f, 0.f, 0.f, 0.f};
    const bool rowok = (row0 + m16) < n;
    #pragma unroll
    for (int kc = 0; kc < 4; ++kc) {
        const bf16x8 afrag2 = *(const bf16x8*)(hw + m16 * 136 + kc * 32 + quad * 8);
        if (rowok)
            *(bf16x8*)(Hbf + (size_t)(row0 + m16) * DIM + kc * 32 + quad * 8) = afrag2;
        const ushort_t* __restrict__ wp2 = Wp2 + (size_t)kc * 1536 + (size_t)lane * 8;
        #pragma unroll
        for (int t = 0; t < 3; ++t) {
            const bf16x8 bfrag = *(const bf16x8*)(wp2 + (size_t)t * 512);
            acc2[t] = __builtin_amdgcn_mfma_f32_16x16x32_bf16(afrag2, bfrag, acc2[t], 0, 0, 0);
        }
    }
    #pragma unroll
    for (int t = 0; t < 3; ++t) {
        const int col = t * 16 + m16;
        if (col >= NCLS) continue;
        #pragma unroll
        for (int r = 0; r < 4; ++r) {
            const int row = row0 + quad * 4 + r;
            if (row < n) Cbf[(size_t)row * NCLS + col] = f2b(acc2[t][r]);
        }
    }
}

// Fused layer-2 gather + right-branch + softmax (R10-proven, one thread/node):
// out[nd] = softmax(mean_{s in N(nd)} Cbf[s] + b2 + Hbf[nd] @ W2_r)
__global__ __launch_bounds__(256) void final_kernel(
    const ushort_t* __restrict__ Hbf, const ushort_t* __restrict__ Cbf,
    const int* __restrict__ row_ptr, const int* __restrict__ eidx,
    const float* __restrict__ W, const float* __restrict__ b2,
    float* __restrict__ out, int n)
{
    int nd = blockIdx.x * 256 + threadIdx.x;
    if (nd >= n) return;
    int j  = row_ptr[nd];
    int je = row_ptr[nd + 1];
    const float id = 1.0f / fmaxf((float)(je - j), 1.0f);
    float lg[NCLS];
    #pragma unroll
    for (int c = 0; c < NCLS; ++c) lg[c] = 0.f;
    for (; j < je; ++j) {
        int s = eidx[j];
        const bf16x8* __restrict__ crow = (const bf16x8*)(Cbf + (size_t)s * NCLS);
        #pragma unroll
        for (int kk = 0; kk < 5; ++kk) {
            bf16x8 v = crow[kk];
            #pragma unroll
            for (int e = 0; e < 8; ++e)
                lg[kk * 8 + e] += b2f((ushort_t)v[e]);
        }
    }
    #pragma unroll
    for (int c = 0; c < NCLS; ++c) lg[c] = fmaf(lg[c], id, b2[c]);
    const ushort_t* __restrict__ h = Hbf + (size_t)nd * DIM;
    for (int k = 0; k < DIM; k += 4) {
        const ushort4 hu = *(const ushort4*)(h + k);
        const float hx = b2f(hu.x), hy = b2f(hu.y), hz = b2f(hu.z), hw = b2f(hu.w);
        const float* __restrict__ w0 = W + (size_t)(k + 0) * NCLS;   // wave-uniform -> s_load
        const float* __restrict__ w1 = W + (size_t)(k + 1) * NCLS;
        const float* __restrict__ w2 = W + (size_t)(k + 2) * NCLS;
        const float* __restrict__ w3 = W + (size_t)(k + 3) * NCLS;
        #pragma unroll
        for (int c = 0; c < NCLS; ++c) {
            float acc = lg[c];
            acc = fmaf(hx, w0[c], acc);
            acc = fmaf(hy, w1[c], acc);
            acc = fmaf(hz, w2[c], acc);
            acc = fmaf(hw, w3[c], acc);
            lg[c] = acc;
        }
    }
    float m = lg[0];
    #pragma unroll
    for (int c = 1; c < NCLS; ++c) m = fmaxf(m, lg[c]);
    float s = 0.f;
    #pragma unroll
    for (int c = 0; c < NCLS; ++c) { lg[c] = __expf(lg[c] - m); s += lg[c]; }
    const float inv = 1.0f / s;
    float* __restrict__ o = out + (size_t)nd * NCLS;
    #pragma unroll
    for (int c = 0; c < NCLS; ++c) o[c] = lg[c] * inv;
}

extern "C" void kernel_launch(void* const* d_in, const int* in_sizes, int n_in,
                              void* d_out, int out_size, void* d_ws, size_t ws_size,
                              hipStream_t stream) {
    const float* x   = (const float*)d_in[0];
    const int*   ei  = (const int*)d_in[1];
    const float* W1l = (const float*)d_in[2];
    const float* W1r = (const float*)d_in[3];
    const float* b1  = (const float*)d_in[4];
    const float* W2l = (const float*)d_in[5];
    const float* W2r = (const float*)d_in[6];
    const float* b2  = (const float*)d_in[7];
    float* out = (float*)d_out;

    const int n = in_sizes[0] / DIM;   // 100000
    const int E = in_sizes[1] / 2;     // 1600000
    const int* src = ei;
    const int* dst = ei + E;
    const int nb = (n + SCAN_B - 1) / SCAN_B;   // 98 scan blocks

    // workspace layout (~80 MB):
    //   xbf (25.6MB) | Hbf (25.6MB) | Cbf (8MB) | xq (12.8MB fp8)
    //   | Wp | Wp2 | eidx[E] | row_ptr[n+1] | deg[n] | pos[n] | bsum[128]
    ushort_t* xbf     = (ushort_t*)d_ws;
    ushort_t* Hbf     = xbf + (size_t)n * DIM;
    ushort_t* Cbf     = Hbf + (size_t)n * DIM;
    unsigned* xq      = (unsigned*)(Cbf + (size_t)n * NCLS);
    ushort_t* Wp      = (ushort_t*)(xq + (size_t)n * 32);
    ushort_t* Wp2     = Wp + 256 * DIM;
    int*      eidx    = (int*)(Wp2 + 4 * 1536);
    int*      row_ptr = eidx + E;
    int*      deg     = row_ptr + (n + 1);
    int*      pos     = deg + n;
    int*      bsum    = pos + n;

    // --- fused prep (cast + weight packs + deg zero) ---
    const int n4 = n * 32;                       // float4 items in x
    const int cb = (n4 + 255) / 256;             // cast blocks
    const int zb = (n + 255) / 256;              // deg-zero blocks
    prep_kernel<<<cb + 152 + zb, 256, 0, stream>>>(x, xbf, xq, W1r, W1l, Wp,
                                                   W2l, Wp2, deg, n4, cb, zb, n);

    // --- CSR build ---
    hist_kernel <<<(E + 255) / 256, 256, 0, stream>>>(dst, deg, E);
    scan1_kernel<<<nb, 256, 0, stream>>>(deg, bsum, n);
    scan3_kernel<<<nb, SCAN_B, 0, stream>>>(deg, bsum, row_ptr, pos, n, nb);
    fill_kernel <<<2048, 256, 0, stream>>>(src, dst, pos, eidx, E, n);

    // --- layer 1 + layer-2-left (fused, incl. neighbor-mean gather) ---
    mfma_gemm_kernel<<<(n + 63) / 64, 256, 0, stream>>>(xbf, xq, row_ptr, eidx,
                                                        Wp, Wp2, b1, Hbf, Cbf, n);

    // --- layer 2: fused gather + right-branch + softmax ---
    final_kernel<<<(n + 255) / 256, 256, 0, stream>>>(Hbf, Cbf, row_ptr, eidx, W2r, b2, out, n);
}

// Round 13
// 316.883 us; speedup vs baseline: 1.8165x; 1.3216x over previous
//
#include <hip/hip_runtime.h>

#define DIM 128
#define NCLS 40
#define NBIN 256
#define BINSH 9
#define CHUNK 4096

typedef unsigned short ushort_t;
typedef __attribute__((ext_vector_type(8))) short bf16x8;
typedef __attribute__((ext_vector_type(4))) float f32x4;

__device__ __forceinline__ ushort_t f2b(float f) {
    union { float f; unsigned u; } v; v.f = f;
    unsigned r = v.u + 0x7FFFu + ((v.u >> 16) & 1u);   // round-to-nearest-even
    return (ushort_t)(r >> 16);
}

__device__ __forceinline__ float b2f(ushort_t b) {
    union { unsigned u; float f; } v; v.u = ((unsigned)b) << 16;
    return v.f;
}

// accumulate 4 fp8(e4m3) values packed in w into a float4
__device__ __forceinline__ void acc_fp8x4(float4& a, int w) {
    a.x += __builtin_amdgcn_cvt_f32_fp8(w, 0);
    a.y += __builtin_amdgcn_cvt_f32_fp8(w, 1);
    a.z += __builtin_amdgcn_cvt_f32_fp8(w, 2);
    a.w += __builtin_amdgcn_cvt_f32_fp8(w, 3);
}

// ---------------- fused prep: cast + packw + packw2 + binCnt-zero -------------
__global__ __launch_bounds__(256) void prep_kernel(
    const float* __restrict__ x, ushort_t* __restrict__ xbf, unsigned* __restrict__ xq,
    const float* __restrict__ W1r, const float* __restrict__ W1l, ushort_t* __restrict__ Wp,
    const float* __restrict__ W2l, ushort_t* __restrict__ Wp2,
    int* __restrict__ binCnt, int n4, int cb)
{
    const int b = blockIdx.x;
    if (b < cb) {
        int i = b * 256 + threadIdx.x;
        if (i >= n4) return;
        f32x4 v = __builtin_nontemporal_load(((const f32x4*)x) + i);
        ushort4 o;
        o.x = f2b(v.x); o.y = f2b(v.y); o.z = f2b(v.z); o.w = f2b(v.w);
        ((ushort4*)xbf)[i] = o;
        int p = __builtin_amdgcn_cvt_pk_fp8_f32(v.x, v.y, 0, false);
        p = __builtin_amdgcn_cvt_pk_fp8_f32(v.z, v.w, p, true);
        xq[i] = (unsigned)p;
    } else if (b < cb + 128) {
        int o = (b - cb) * 256 + threadIdx.x;   // 0..32767
        int j    = o & 7;
        int lane = (o >> 3) & 63;
        int t    = (o >> 9) & 7;
        int kc   = o >> 12;
        int k = kc * 32 + (lane >> 4) * 8 + j;
        int nn = t * 16 + (lane & 15);
        float v = (k < DIM) ? W1r[k * DIM + nn] : W1l[(k - DIM) * DIM + nn];
        Wp[o] = f2b(v);
    } else if (b < cb + 152) {
        int o = (b - cb - 128) * 256 + threadIdx.x;   // 0..6143
        int j    = o & 7;
        int lane = (o >> 3) & 63;
        int rem  = o >> 9;
        int t    = rem % 3;
        int kc   = rem / 3;
        int k  = kc * 32 + (lane >> 4) * 8 + j;
        int nn = t * 16 + (lane & 15);
        Wp2[o] = (nn < NCLS) ? f2b(W2l[k * NCLS + nn]) : (ushort_t)0;
    } else {
        binCnt[threadIdx.x] = 0;
    }
}

// ---------------- CSR build via binned counting sort ----------------

// A1: per-bin edge counts (bin = dst >> 9)
__global__ __launch_bounds__(256) void bincount_kernel(const int* __restrict__ dst,
                                                       int* __restrict__ binCnt, int E) {
    __shared__ int hist[NBIN];
    hist[threadIdx.x] = 0;
    __syncthreads();
    const int tid = blockIdx.x * 256 + threadIdx.x;
    const int stride = gridDim.x * 256;
    for (int e = tid; e < E; e += stride)
        atomicAdd(&hist[__builtin_nontemporal_load(dst + e) >> BINSH], 1);
    __syncthreads();
    if (hist[threadIdx.x]) atomicAdd(&binCnt[threadIdx.x], hist[threadIdx.x]);
}

// scan of 256 bin counts -> binBase[257], binCtr (reservation counters), row_ptr[n]=E
__global__ __launch_bounds__(NBIN) void binscan_kernel(const int* __restrict__ binCnt,
                                                       int* __restrict__ binBase,
                                                       int* __restrict__ binCtr,
                                                       int* __restrict__ row_ptr, int n) {
    __shared__ int sc[NBIN];
    const int t = threadIdx.x;
    sc[t] = binCnt[t];
    __syncthreads();
    for (int off = 1; off < NBIN; off <<= 1) {
        int v = (t >= off) ? sc[t - off] : 0;
        __syncthreads();
        sc[t] += v;
        __syncthreads();
    }
    int excl = (t == 0) ? 0 : sc[t - 1];
    binBase[t] = excl;
    binCtr[t]  = excl;
    if (t == NBIN - 1) { binBase[NBIN] = sc[t]; row_ptr[n] = sc[t]; }
}

// A2: scatter (src,dst) pairs bucket-major. LDS-staged 4096-edge chunks; one
// global atomic per (chunk,bin) reserves a contiguous run -> ~coalesced writes.
__global__ __launch_bounds__(256) void binscatter_kernel(
    const int* __restrict__ src, const int* __restrict__ dst,
    int* __restrict__ binCtr, int2* __restrict__ pairs, int E)
{
    __shared__ int ss[CHUNK];    // 16 KB
    __shared__ int sd[CHUNK];    // 16 KB
    __shared__ int hist[NBIN];
    __shared__ int base[NBIN];
    __shared__ int cnt[NBIN];
    const int nchunk = (E + CHUNK - 1) / CHUNK;
    for (int c = blockIdx.x; c < nchunk; c += gridDim.x) {
        const int e0 = c * CHUNK;
        const int m = min(CHUNK, E - e0);
        for (int i = threadIdx.x; i < m; i += 256) {
            ss[i] = __builtin_nontemporal_load(src + e0 + i);
            sd[i] = __builtin_nontemporal_load(dst + e0 + i);
        }
        hist[threadIdx.x] = 0;
        cnt[threadIdx.x] = 0;
        __syncthreads();
        for (int i = threadIdx.x; i < m; i += 256)
            atomicAdd(&hist[sd[i] >> BINSH], 1);
        __syncthreads();
        base[threadIdx.x] = hist[threadIdx.x]
            ? atomicAdd(&binCtr[threadIdx.x], hist[threadIdx.x]) : 0;
        __syncthreads();
        for (int i = threadIdx.x; i < m; i += 256) {
            int d = sd[i];
            int b = d >> BINSH;
            int off = base[b] + atomicAdd(&cnt[b], 1);
            pairs[off] = make_int2(ss[i], d);
        }
        __syncthreads();
    }
}

// B: block b finalizes bin b (512 nodes): local deg hist -> scan -> row_ptr,
// then scatters src into its PRIVATE 32KB eidx window (one block per window
// -> full-line writebacks, no cross-XCD splitting).
__global__ __launch_bounds__(256) void bincsr_kernel(
    const int2* __restrict__ pairs, const int* __restrict__ binBase,
    int* __restrict__ row_ptr, int* __restrict__ eidx, int n)
{
    __shared__ int deg[512];
    __shared__ int sc[512];
    __shared__ int cnt[512];
    const int b  = blockIdx.x;
    const int lo = binBase[b];
    const int hi = binBase[b + 1];
    const int nlo = b << BINSH;
    const int t = threadIdx.x;
    deg[t] = 0; deg[t + 256] = 0;
    cnt[t] = 0; cnt[t + 256] = 0;
    __syncthreads();
    for (int e = lo + t; e < hi; e += 256) {
        int2 p = pairs[e];
        atomicAdd(&deg[p.y - nlo], 1);
    }
    __syncthreads();
    sc[t] = deg[t];
    sc[t + 256] = deg[t + 256];
    __syncthreads();
    for (int off = 1; off < 512; off <<= 1) {    // inclusive HS scan over 512
        int v0 = (t >= off) ? sc[t - off] : 0;
        int v1 = sc[t + 256 - off];
        __syncthreads();
        sc[t] += v0;
        sc[t + 256] += v1;
        __syncthreads();
    }
    // row_ptr[node] = lo + exclusive_prefix
    {
        int node0 = nlo + t;
        int node1 = nlo + t + 256;
        if (node0 < n) row_ptr[node0] = lo + sc[t] - deg[t];
        if (node1 < n) row_ptr[node1] = lo + sc[t + 256] - deg[t + 256];
    }
    for (int e = lo + t; e < hi; e += 256) {
        int2 p = pairs[e];
        int dl = p.y - nlo;
        int slot = sc[dl] - deg[dl] + atomicAdd(&cnt[dl], 1);
        eidx[lo + slot] = p.x;
    }
}

// ---------------- compute (R10-proven forms) ----------------

// mxbf[node] = mean over CSR neighbors of xq[src] (fp8 in, fp32 accum, bf16 out)
__global__ __launch_bounds__(256) void gather128_kernel(
    const unsigned* __restrict__ xq, const int* __restrict__ row_ptr,
    const int* __restrict__ eidx, ushort_t* __restrict__ Bbf, int n)
{
    int t = blockIdx.x * 256 + threadIdx.x;
    int node = t >> 5;
    if (node >= n) return;
    int q = t & 31;
    int j  = row_ptr[node];
    int je = row_ptr[node + 1];
    const float id = 1.0f / fmaxf((float)(je - j), 1.0f);
    float4 acc = make_float4(0.f, 0.f, 0.f, 0.f);
    for (; j + 3 < je; j += 4) {
        int s0 = eidx[j], s1 = eidx[j + 1], s2 = eidx[j + 2], s3 = eidx[j + 3];
        int w0 = (int)xq[(size_t)s0 * 32 + q];
        int w1 = (int)xq[(size_t)s1 * 32 + q];
        int w2 = (int)xq[(size_t)s2 * 32 + q];
        int w3 = (int)xq[(size_t)s3 * 32 + q];
        acc_fp8x4(acc, w0); acc_fp8x4(acc, w1);
        acc_fp8x4(acc, w2); acc_fp8x4(acc, w3);
    }
    for (; j < je; ++j) {
        int s0 = eidx[j];
        acc_fp8x4(acc, (int)xq[(size_t)s0 * 32 + q]);
    }
    ushort4 o;
    o.x = f2b(acc.x * id); o.y = f2b(acc.y * id);
    o.z = f2b(acc.z * id); o.w = f2b(acc.w * id);
    ((ushort4*)(Bbf + (size_t)node * DIM))[q] = o;
}

// Fused layer-1 + layer-2-left (R10-proven)
__global__ __launch_bounds__(256) void mfma_gemm_kernel(
    const ushort_t* __restrict__ xbf, const ushort_t* __restrict__ mxbf,
    const ushort_t* __restrict__ Wp, const ushort_t* __restrict__ Wp2,
    const float* __restrict__ bias,
    ushort_t* __restrict__ Hbf, ushort_t* __restrict__ Cbf, int n)
{
    __shared__ ushort_t hl[4][16 * 136];   // 16 rows x 136 (pad 8) bf16 per wave
    const int wave = threadIdx.x >> 6;
    const int lane = threadIdx.x & 63;
    const int m16  = lane & 15;
    const int quad = lane >> 4;
    const int row0 = blockIdx.x * 64 + wave * 16;
    int arow = row0 + m16;
    if (arow >= n) arow = n - 1;          // clamp; OOB rows never stored
    f32x4 acc[8];
    #pragma unroll
    for (int t = 0; t < 8; ++t) acc[t] = (f32x4){0.f, 0.f, 0.f, 0.f};
    const ushort_t* __restrict__ xrow = xbf  + (size_t)arow * DIM;
    const ushort_t* __restrict__ mrow = mxbf + (size_t)arow * DIM;
    #pragma unroll
    for (int kc = 0; kc < 8; ++kc) {
        const int kcol = (kc & 3) * 32 + quad * 8;
        const bf16x8 afrag = *(const bf16x8*)((kc < 4 ? xrow : mrow) + kcol);
        const ushort_t* __restrict__ wp = Wp + (size_t)kc * 4096 + (size_t)lane * 8;
        #pragma unroll
        for (int t = 0; t < 8; ++t) {
            const bf16x8 bfrag = *(const bf16x8*)(wp + (size_t)t * 512);
            acc[t] = __builtin_amdgcn_mfma_f32_16x16x32_bf16(afrag, bfrag, acc[t], 0, 0, 0);
        }
    }
    ushort_t* __restrict__ hw = hl[wave];
    #pragma unroll
    for (int t = 0; t < 8; ++t) {
        const int col = t * 16 + m16;
        const float bv = bias[col];
        #pragma unroll
        for (int r = 0; r < 4; ++r) {
            hw[(quad * 4 + r) * 136 + col] = f2b(fmaxf(acc[t][r] + bv, 0.f));
        }
    }
    f32x4 acc2[3];
    #pragma unroll
    for (int t = 0; t < 3; ++t) acc2[t] = (f32x4){0.f, 0.f, 0.f, 0.f};
    const bool rowok = (row0 + m16) < n;
    #pragma unroll
    for (int kc = 0; kc < 4; ++kc) {
        const bf16x8 afrag2 = *(const bf16x8*)(hw + m16 * 136 + kc * 32 + quad * 8);
        if (rowok)
            *(bf16x8*)(Hbf + (size_t)(row0 + m16) * DIM + kc * 32 + quad * 8) = afrag2;
        const ushort_t* __restrict__ wp2 = Wp2 + (size_t)kc * 1536 + (size_t)lane * 8;
        #pragma unroll
        for (int t = 0; t < 3; ++t) {
            const bf16x8 bfrag = *(const bf16x8*)(wp2 + (size_t)t * 512);
            acc2[t] = __builtin_amdgcn_mfma_f32_16x16x32_bf16(afrag2, bfrag, acc2[t], 0, 0, 0);
        }
    }
    #pragma unroll
    for (int t = 0; t < 3; ++t) {
        const int col = t * 16 + m16;
        if (col >= NCLS) continue;
        #pragma unroll
        for (int r = 0; r < 4; ++r) {
            const int row = row0 + quad * 4 + r;
            if (row < n) Cbf[(size_t)row * NCLS + col] = f2b(acc2[t][r]);
        }
    }
}

// Fused layer-2 gather + right-branch + softmax (R10-proven, one thread/node)
__global__ __launch_bounds__(256) void final_kernel(
    const ushort_t* __restrict__ Hbf, const ushort_t* __restrict__ Cbf,
    const int* __restrict__ row_ptr, const int* __restrict__ eidx,
    const float* __restrict__ W, const float* __restrict__ b2,
    float* __restrict__ out, int n)
{
    int nd = blockIdx.x * 256 + threadIdx.x;
    if (nd >= n) return;
    int j  = row_ptr[nd];
    int je = row_ptr[nd + 1];
    const float id = 1.0f / fmaxf((float)(je - j), 1.0f);
    float lg[NCLS];
    #pragma unroll
    for (int c = 0; c < NCLS; ++c) lg[c] = 0.f;
    for (; j < je; ++j) {
        int s = eidx[j];
        const bf16x8* __restrict__ crow = (const bf16x8*)(Cbf + (size_t)s * NCLS);
        #pragma unroll
        for (int kk = 0; kk < 5; ++kk) {
            bf16x8 v = crow[kk];
            #pragma unroll
            for (int e = 0; e < 8; ++e)
                lg[kk * 8 + e] += b2f((ushort_t)v[e]);
        }
    }
    #pragma unroll
    for (int c = 0; c < NCLS; ++c) lg[c] = fmaf(lg[c], id, b2[c]);
    const ushort_t* __restrict__ h = Hbf + (size_t)nd * DIM;
    for (int k = 0; k < DIM; k += 4) {
        const ushort4 hu = *(const ushort4*)(h + k);
        const float hx = b2f(hu.x), hy = b2f(hu.y), hz = b2f(hu.z), hw = b2f(hu.w);
        const float* __restrict__ w0 = W + (size_t)(k + 0) * NCLS;   // wave-uniform -> s_load
        const float* __restrict__ w1 = W + (size_t)(k + 1) * NCLS;
        const float* __restrict__ w2 = W + (size_t)(k + 2) * NCLS;
        const float* __restrict__ w3 = W + (size_t)(k + 3) * NCLS;
        #pragma unroll
        for (int c = 0; c < NCLS; ++c) {
            float acc = lg[c];
            acc = fmaf(hx, w0[c], acc);
            acc = fmaf(hy, w1[c], acc);
            acc = fmaf(hz, w2[c], acc);
            acc = fmaf(hw, w3[c], acc);
            lg[c] = acc;
        }
    }
    float m = lg[0];
    #pragma unroll
    for (int c = 1; c < NCLS; ++c) m = fmaxf(m, lg[c]);
    float s = 0.f;
    #pragma unroll
    for (int c = 0; c < NCLS; ++c) { lg[c] = __expf(lg[c] - m); s += lg[c]; }
    const float inv = 1.0f / s;
    float* __restrict__ o = out + (size_t)nd * NCLS;
    #pragma unroll
    for (int c = 0; c < NCLS; ++c) o[c] = lg[c] * inv;
}

extern "C" void kernel_launch(void* const* d_in, const int* in_sizes, int n_in,
                              void* d_out, int out_size, void* d_ws, size_t ws_size,
                              hipStream_t stream) {
    const float* x   = (const float*)d_in[0];
    const int*   ei  = (const int*)d_in[1];
    const float* W1l = (const float*)d_in[2];
    const float* W1r = (const float*)d_in[3];
    const float* b1  = (const float*)d_in[4];
    const float* W2l = (const float*)d_in[5];
    const float* W2r = (const float*)d_in[6];
    const float* b2  = (const float*)d_in[7];
    float* out = (float*)d_out;

    const int n = in_sizes[0] / DIM;   // 100000
    const int E = in_sizes[1] / 2;     // 1600000
    const int* src = ei;
    const int* dst = ei + E;

    // workspace layout (~118 MB):
    //   xbf (25.6M) | mxbf (25.6M) | Hbf (25.6M) | Cbf (8M) | xq (12.8M)
    //   | Wp (64K) | Wp2 (12K) | eidx[E] | pairs[E] int2 (12.8M)
    //   | row_ptr[n+1] | binCnt[256] | binBase[257] | binCtr[256]
    ushort_t* xbf     = (ushort_t*)d_ws;
    ushort_t* mxbf    = xbf + (size_t)n * DIM;
    ushort_t* Hbf     = mxbf + (size_t)n * DIM;
    ushort_t* Cbf     = Hbf + (size_t)n * DIM;
    unsigned* xq      = (unsigned*)(Cbf + (size_t)n * NCLS);
    ushort_t* Wp      = (ushort_t*)(xq + (size_t)n * 32);
    ushort_t* Wp2     = Wp + 256 * DIM;
    int*      eidx    = (int*)(Wp2 + 4 * 1536);
    int2*     pairs   = (int2*)(eidx + E);
    int*      row_ptr = (int*)(pairs + E);
    int*      binCnt  = row_ptr + (n + 1);
    int*      binBase = binCnt + NBIN;
    int*      binCtr  = binBase + NBIN + 1;

    // --- fused prep (cast + weight packs + binCnt zero) ---
    const int n4 = n * 32;                       // float4 items in x
    const int cb = (n4 + 255) / 256;             // cast blocks
    prep_kernel<<<cb + 153, 256, 0, stream>>>(x, xbf, xq, W1r, W1l, Wp,
                                              W2l, Wp2, binCnt, n4, cb);

    // --- CSR build via binned counting sort ---
    bincount_kernel  <<<512, 256, 0, stream>>>(dst, binCnt, E);
    binscan_kernel   <<<1, NBIN, 0, stream>>>(binCnt, binBase, binCtr, row_ptr, n);
    binscatter_kernel<<<512, 256, 0, stream>>>(src, dst, binCtr, pairs, E);
    bincsr_kernel    <<<NBIN, 256, 0, stream>>>(pairs, binBase, row_ptr, eidx, n);

    // --- layer 1 + layer-2-left ---
    {
        long long t = (long long)n * 32;
        gather128_kernel<<<(int)((t + 255) / 256), 256, 0, stream>>>(xq, row_ptr, eidx, mxbf, n);
    }
    mfma_gemm_kernel<<<(n + 63) / 64, 256, 0, stream>>>(xbf, mxbf, Wp, Wp2, b1, Hbf, Cbf, n);

    // --- layer 2: fused gather + right-branch + softmax ---
    final_kernel<<<(n + 255) / 256, 256, 0, stream>>>(Hbf, Cbf, row_ptr, eidx, W2r, b2, out, n);
}